// Round 11
// baseline (413.667 us; speedup 1.0000x reference)
//
#include <hip/hip_runtime.h>

// ---------------- problem constants ----------------
constexpr int B_  = 32;
constexpr int T_  = 512;
constexpr int D_  = 1024;
constexpr int NH_ = 16;
constexpr int DH_ = 64;
constexpr int F_  = 4096;
constexpr int BT_ = B_ * T_;   // 16384

typedef __attribute__((ext_vector_type(8))) short bf16x8;
typedef __attribute__((ext_vector_type(4))) float f32x4;
typedef __attribute__((ext_vector_type(8))) int i32x8;

#define DEVI __device__ __forceinline__

DEVI unsigned short f2bf(float f) {
  union { float f; unsigned u; } uf; uf.f = f;
  unsigned r = uf.u + 0x7fffu + ((uf.u >> 16) & 1u);   // RNE
  return (unsigned short)(r >> 16);
}
DEVI float b2f(unsigned short h) {
  union { unsigned u; float f; } uf; uf.u = ((unsigned)h) << 16;
  return uf.f;
}
DEVI unsigned char f2fp8(float f) {   // OCP e4m3, HW RNE+sat
  return (unsigned char)(__builtin_amdgcn_cvt_pk_fp8_f32(f, f, 0, false) & 0xFF);
}
// async global->LDS, 16B per lane.
DEVI void gload16(const void* g, void* l) {
  __builtin_amdgcn_global_load_lds(
      (const __attribute__((address_space(1))) void*)(uintptr_t)g,
      (__attribute__((address_space(3))) void*)(unsigned)(uintptr_t)l, 16, 0, 0);
}
DEVI i32x8 ld32(const char* p0, const char* p1) {
  int4 lo = *(const int4*)p0, hi = *(const int4*)p1;
  i32x8 r;
  r[0] = lo.x; r[1] = lo.y; r[2] = lo.z; r[3] = lo.w;
  r[4] = hi.x; r[5] = hi.y; r[6] = hi.z; r[7] = hi.w;
  return r;
}

// ---------------- pack (PE fused): q_pe = q + pe ; k_pe = q + 2*pe   (bf16)
__global__ void pack_kernel(const float* __restrict__ q,
                            unsigned short* __restrict__ q_pe, unsigned short* __restrict__ k_pe) {
  long i = ((long)blockIdx.x * 256 + threadIdx.x) * 4;
  const float4 qv = *(const float4*)(q + i);
  int t = (int)((i >> 10) & 511);
  int j0 = (int)(i & 1023);
  float pvv[4];
#pragma unroll
  for (int u = 0; u < 4; u++) {
    int j = j0 + u;
    float inv = exp2f(-(2.0f * (float)j / 1024.0f) * 13.2877123795494f); // log2(10000)
    float ang = (float)t * inv;
    pvv[u] = ((j & 1) ? cosf(ang) : sinf(ang)) * 32.0f;
  }
  ushort4 a, b;
  a.x = f2bf(qv.x + pvv[0]); a.y = f2bf(qv.y + pvv[1]);
  a.z = f2bf(qv.z + pvv[2]); a.w = f2bf(qv.w + pvv[3]);
  b.x = f2bf(qv.x + 2.f * pvv[0]); b.y = f2bf(qv.y + 2.f * pvv[1]);
  b.z = f2bf(qv.z + 2.f * pvv[2]); b.w = f2bf(qv.w + 2.f * pvv[3]);
  *(ushort4*)(q_pe + i) = a;
  *(ushort4*)(k_pe + i) = b;
}

// merged weight prep: z in {0:Wq,1:Wk,2:Wv} -> Wt[N][K] bf16 (z==1 also emits Wkbf row-major);
// z==3: fw1 -> fw1t8[N][K] fp8 of (fw1 * 64)  [unit-scale MX trick]
__global__ void prep_w(const float* __restrict__ Wq, const float* __restrict__ Wk,
                       const float* __restrict__ Wv, const float* __restrict__ fw1,
                       unsigned short* __restrict__ Wqt, unsigned short* __restrict__ Wkt,
                       unsigned short* __restrict__ Wvt, unsigned char* __restrict__ fw1t8,
                       unsigned short* __restrict__ Wkbf) {
  const int z = blockIdx.z;
  if (z < 3 && blockIdx.x >= 32) return;
  const float* W = (z == 0) ? Wq : (z == 1) ? Wk : (z == 2) ? Wv : fw1;
  unsigned short* Wt = (z == 0) ? Wqt : (z == 1) ? Wkt : Wvt;
  const int N = (z == 3) ? F_ : D_;       // cols of W
  __shared__ float tile[32][33];
  int tx = threadIdx.x & 31, ty = threadIdx.x >> 5;
  int bx = blockIdx.x, by = blockIdx.y;
  for (int i = 0; i < 4; i++) {
    int r = by * 32 + ty + i * 8;
    float v = W[(long)r * N + bx * 32 + tx];
    tile[ty + i * 8][tx] = v;
    if (z == 1) Wkbf[(long)r * D_ + bx * 32 + tx] = f2bf(v);
  }
  __syncthreads();
  for (int i = 0; i < 4; i++) {
    int r = bx * 32 + ty + i * 8;
    if (z == 3) fw1t8[(long)r * D_ + by * 32 + tx] = f2fp8(tile[tx][ty + i * 8] * 64.0f);
    else        Wt[(long)r * D_ + by * 32 + tx] = f2bf(tile[tx][ty + i * 8]);
  }
}

// ---------------- small m97-style 128x128 GEMM (only for Wkv = Wv^T @ Wk^T fold)
template <int EPI>
__global__ __launch_bounds__(256) void gemm_bt(
    const unsigned short* __restrict__ A0, const unsigned short* __restrict__ Bt0,
    unsigned short* __restrict__ C0, float* __restrict__ hacc, int M, int N, int K) {
  __shared__ unsigned short As[128 * 32];
  __shared__ unsigned short Bs[128 * 32];
  const unsigned short* A  = A0;
  const unsigned short* Bt = Bt0;
  unsigned short* C        = C0;

  const int tid = threadIdx.x;
  const int lane = tid & 63, w = tid >> 6;
  const int wr = w >> 1, wc = w & 1;
  const int l15 = lane & 15, lhi = lane >> 4;
  const int brow = blockIdx.y * 128, bcol = blockIdx.x * 128;

  f32x4 acc[4][4] = {};
  const int o = tid * 16;
  const int srow = o >> 6;
  const int skel = (o & 63) >> 1;

  for (int kk = 0; kk < K; kk += 32) {
    gload16(A + (long)(brow + srow) * K + kk + skel,        (char*)As + o);
    gload16(A + (long)(brow + srow + 64) * K + kk + skel,   (char*)As + o + 4096);
    gload16(Bt + (long)(bcol + srow) * K + kk + skel,       (char*)Bs + o);
    gload16(Bt + (long)(bcol + srow + 64) * K + kk + skel,  (char*)Bs + o + 4096);
    __syncthreads();
    bf16x8 af[4], bfr[4];
    for (int m = 0; m < 4; m++)
      af[m] = *(const bf16x8*)((const char*)As + ((wr * 64 + m * 16 + l15) * 64 + lhi * 16));
    for (int n = 0; n < 4; n++)
      bfr[n] = *(const bf16x8*)((const char*)Bs + ((wc * 64 + n * 16 + l15) * 64 + lhi * 16));
    for (int m = 0; m < 4; m++)
      for (int n = 0; n < 4; n++)
        acc[m][n] = __builtin_amdgcn_mfma_f32_16x16x32_bf16(af[m], bfr[n], acc[m][n], 0, 0, 0);
    __syncthreads();
  }

  for (int m = 0; m < 4; m++)
    for (int n = 0; n < 4; n++) {
      int row = brow + wr * 64 + m * 16 + lhi * 4;
      int col = bcol + wc * 64 + n * 16 + l15;
      for (int r = 0; r < 4; r++)
        C[(long)(row + r) * N + col] = f2bf(acc[m][n][r]);
    }
}

// ---------------- 256x256 8-phase GEMM bf16 (R5 schedule) — QKV projections.
// EPI==0: z<2 store bf16 C; z==2 store V transposed into vt[(b*16+h)*64+j][t] (coalesced via LDS).
// L (optional): per-batch live-row count; row-tile 1 of batch b is dead if L[b] <= 256.
template <int EPI>
__global__ __launch_bounds__(512, 2) void gemm8(
    const unsigned short* __restrict__ A0, const unsigned short* __restrict__ Bt0, unsigned short* __restrict__ C0,
    const unsigned short* __restrict__ A1, const unsigned short* __restrict__ Bt1, unsigned short* __restrict__ C1,
    const unsigned short* __restrict__ A2, const unsigned short* __restrict__ Bt2, unsigned short* __restrict__ C2,
    float* __restrict__ hacc, int N,
    const int* __restrict__ L0, const int* __restrict__ L1, const int* __restrict__ L2) {
  constexpr int K = 1024, NK = 16, NI = 8;
  __shared__ char lds[2][2][32768];

  const int z = blockIdx.z;
  const unsigned short* A  = (z == 0) ? A0  : (z == 1 ? A1  : A2);
  const unsigned short* Bt = (z == 0) ? Bt0 : (z == 1 ? Bt1 : Bt2);
  unsigned short* C        = (z == 0) ? C0  : (z == 1 ? C1  : C2);
  const int* L             = (z == 0) ? L0  : (z == 1 ? L1  : L2);

  const long brow = (long)blockIdx.x * 256, bcol = (long)blockIdx.y * 256;
  if (L && (brow & 256) && L[brow >> 9] <= 256) return;   // dead row-tile

  const int tid = threadIdx.x;
  const int lane = tid & 63, w = tid >> 6;
  const int wm = w >> 2, wn = w & 3;
  const int l15 = lane & 15, lhi = lane >> 4;

  const int drow = (tid * 16) >> 7;
  const int dcol = ((tid * 16) & 127) ^ ((drow & 7) << 4);
  const int sw   = (l15 & 7) << 4;

  f32x4 acc[8][4] = {};
  bf16x8 bfr[4][2], af[2][2];

  auto STAGE = [&](const unsigned short* __restrict__ P, long tb, int kt, int h, int buf, int op) {
    const unsigned short* g = P + (tb + h * 128 + drow) * (long)K + kt * 64 + (dcol >> 1);
    char* l = &lds[buf][op][h * 16384 + tid * 16];
    gload16(g, l);
    gload16(g + 64L * K, l + 8192);
  };
  auto LDA = [&](int buf, int q) {
#pragma unroll
    for (int mi = 0; mi < 2; mi++) {
      int row = wm * 128 + (q * 2 + mi) * 16 + l15;
#pragma unroll
      for (int kk = 0; kk < 2; kk++)
        af[mi][kk] = *(const bf16x8*)(&lds[buf][0][0] + (row << 7) + ((kk * 64 + lhi * 16) ^ sw));
    }
  };
  auto LDB = [&](int buf) {
#pragma unroll
    for (int n = 0; n < 4; n++) {
      int row = wn * 64 + n * 16 + l15;
#pragma unroll
      for (int kk = 0; kk < 2; kk++)
        bfr[n][kk] = *(const bf16x8*)(&lds[buf][1][0] + (row << 7) + ((kk * 64 + lhi * 16) ^ sw));
    }
  };
  auto MFMAQ = [&](int q) {
    __builtin_amdgcn_s_setprio(1);
#pragma unroll
    for (int mi = 0; mi < 2; mi++)
#pragma unroll
      for (int n = 0; n < 4; n++)
#pragma unroll
        for (int kk = 0; kk < 2; kk++)
          acc[q * 2 + mi][n] =
              __builtin_amdgcn_mfma_f32_16x16x32_bf16(af[mi][kk], bfr[n][kk], acc[q * 2 + mi][n], 0, 0, 0);
    __builtin_amdgcn_s_setprio(0);
  };
#define BAR() __builtin_amdgcn_s_barrier()
#define GATE4() asm volatile("s_waitcnt vmcnt(4)" ::: "memory")

  STAGE(A, brow, 0, 0, 0, 0);  STAGE(A, brow, 0, 1, 0, 0);
  STAGE(Bt, bcol, 0, 0, 0, 1); STAGE(Bt, bcol, 0, 1, 0, 1);
  STAGE(Bt, bcol, 1, 0, 1, 1); STAGE(Bt, bcol, 1, 1, 1, 1);
  GATE4();
  BAR();

  for (int i = 0; i < NI; ++i) {
    const int k1 = 2 * i + 1;
    const int ka = (2 * i + 2) & (NK - 1);
    const int kb = (2 * i + 3) & (NK - 1);
    LDA(0, 0); LDB(0); STAGE(A, brow, k1, 0, 1, 0);
    BAR(); MFMAQ(0); BAR();
    LDA(0, 1);         STAGE(A, brow, k1, 1, 1, 0);
    BAR(); MFMAQ(1); BAR();
    LDA(0, 2);         STAGE(Bt, bcol, ka, 0, 0, 1);
    BAR(); MFMAQ(2); BAR();
    LDA(0, 3);         STAGE(Bt, bcol, ka, 1, 0, 1);
    BAR(); MFMAQ(3);
    GATE4();
    BAR();
    LDA(1, 0); LDB(1); STAGE(A, brow, ka, 0, 0, 0);
    BAR(); MFMAQ(0); BAR();
    LDA(1, 1);         STAGE(A, brow, ka, 1, 0, 0);
    BAR(); MFMAQ(1); BAR();
    LDA(1, 2);         STAGE(Bt, bcol, kb, 0, 1, 1);
    BAR(); MFMAQ(2); BAR();
    LDA(1, 3);         STAGE(Bt, bcol, kb, 1, 1, 1);
    BAR(); MFMAQ(3);
    GATE4();
    BAR();
  }
#undef BAR
#undef GATE4

  if (EPI == 0) {
    if (z == 2) {
      asm volatile("s_waitcnt vmcnt(0)" ::: "memory");
      __builtin_amdgcn_s_barrier();
      char* tl = &lds[0][0][0] + (w << 14);
#pragma unroll
      for (int m = 0; m < 8; m++)
#pragma unroll
        for (int n = 0; n < 4; n++) {
          int cl = n * 16 + l15;
#pragma unroll
          for (int r = 0; r < 4; r++) {
            int tofs = m * 16 + lhi * 4 + r;
            *(unsigned short*)(tl + cl * 256 + ((tofs * 2) ^ ((cl & 7) << 4))) = f2bf(acc[m][n][r]);
          }
        }
      asm volatile("" ::: "memory");
      const int bb = (int)(brow >> 9), t0 = (int)(brow & 511);
#pragma unroll
      for (int rr = 0; rr < 16; rr++) {
        int row = rr * 4 + lhi;
        bf16x8 v = *(const bf16x8*)(tl + row * 256 + ((l15 * 16) ^ ((row & 7) << 4)));
        int gcol = (int)bcol + wn * 64 + row;
        long vtrow = ((long)(bb * NH_ + (gcol >> 6))) * DH_ + (gcol & 63);
        *(bf16x8*)(C + vtrow * T_ + t0 + wm * 128 + l15 * 8) = v;
      }
    } else {
#pragma unroll
      for (int m = 0; m < 8; m++)
#pragma unroll
        for (int n = 0; n < 4; n++) {
          long row = brow + wm * 128 + m * 16 + lhi * 4;
          long col = bcol + wn * 64 + n * 16 + l15;
#pragma unroll
          for (int r = 0; r < 4; r++)
            C[(row + r) * (long)N + col] = f2bf(acc[m][n][r]);
        }
    }
  } else {
    const int batch = (int)(brow >> 9);
#pragma unroll
    for (int n = 0; n < 4; n++) {
      float t = 0.f;
#pragma unroll
      for (int m = 0; m < 8; m++)
#pragma unroll
        for (int r = 0; r < 4; r++) t += fmaxf(acc[m][n][r], 0.f);
      t += __shfl_xor(t, 16);
      t += __shfl_xor(t, 32);
      if (lane < 16)
        atomicAdd(hacc + (long)batch * F_ + bcol + wn * 64 + n * 16 + l15, t);
    }
  }
}

// ---------------- FFN1 in fp8: hacc[b][f] = sum_t relu(res8 @ fw1t8^T)  (values carry x64 from fw1)
// Same R5 schedule, BK=128 fp8 == identical byte geometry; K-tiles 16 -> 8; unit e8m0 scales (0x7F).
__global__ __launch_bounds__(512, 2) void gemmf8(
    const unsigned char* __restrict__ A, const unsigned char* __restrict__ Bt,
    float* __restrict__ hacc) {
  constexpr int K = 1024, NKT = 8, NI = 4;
  __shared__ char lds[2][2][32768];
  const long brow = (long)blockIdx.x * 256, bcol = (long)blockIdx.y * 256;
  const int tid = threadIdx.x;
  const int lane = tid & 63, w = tid >> 6;
  const int wm = w >> 2, wn = w & 3;
  const int l15 = lane & 15, lhi = lane >> 4;

  const int drow = (tid * 16) >> 7;
  const int dcol = ((tid * 16) & 127) ^ ((drow & 7) << 4);
  const int sw   = (l15 & 7) << 4;

  f32x4 acc[8][4] = {};
  i32x8 af[2], bfr[4];

  auto STAGE = [&](const unsigned char* __restrict__ P, long tb, int kt, int h, int buf, int op) {
    const unsigned char* g = P + (tb + h * 128 + drow) * (long)K + kt * 128 + dcol;
    char* l = &lds[buf][op][h * 16384 + tid * 16];
    gload16(g, l);
    gload16(g + 64L * K, l + 8192);
  };
  auto LDA = [&](int buf, int q) {
#pragma unroll
    for (int mi = 0; mi < 2; mi++) {
      int row = wm * 128 + (q * 2 + mi) * 16 + l15;
      const char* base = &lds[buf][0][0] + (row << 7);
      af[mi] = ld32(base + ((lhi * 32) ^ sw), base + ((lhi * 32 + 16) ^ sw));
    }
  };
  auto LDB = [&](int buf) {
#pragma unroll
    for (int n = 0; n < 4; n++) {
      int row = wn * 64 + n * 16 + l15;
      const char* base = &lds[buf][1][0] + (row << 7);
      bfr[n] = ld32(base + ((lhi * 32) ^ sw), base + ((lhi * 32 + 16) ^ sw));
    }
  };
  auto MFMAQ = [&](int q) {
    __builtin_amdgcn_s_setprio(1);
#pragma unroll
    for (int mi = 0; mi < 2; mi++)
#pragma unroll
      for (int n = 0; n < 4; n++)
        acc[q * 2 + mi][n] = __builtin_amdgcn_mfma_scale_f32_16x16x128_f8f6f4(
            af[mi], bfr[n], acc[q * 2 + mi][n], 0, 0,
            0, 0x7F7F7F7F, 0, 0x7F7F7F7F);   // fp8 x fp8, unit e8m0 scales
    __builtin_amdgcn_s_setprio(0);
  };
#define BAR() __builtin_amdgcn_s_barrier()
#define GATE4() asm volatile("s_waitcnt vmcnt(4)" ::: "memory")

  STAGE(A, brow, 0, 0, 0, 0);  STAGE(A, brow, 0, 1, 0, 0);
  STAGE(Bt, bcol, 0, 0, 0, 1); STAGE(Bt, bcol, 0, 1, 0, 1);
  STAGE(Bt, bcol, 1, 0, 1, 1); STAGE(Bt, bcol, 1, 1, 1, 1);
  GATE4();
  BAR();

  for (int i = 0; i < NI; ++i) {
    const int k1 = 2 * i + 1;
    const int ka = (2 * i + 2) & (NKT - 1);
    const int kb = (2 * i + 3) & (NKT - 1);
    LDA(0, 0); LDB(0); STAGE(A, brow, k1, 0, 1, 0);
    BAR(); MFMAQ(0); BAR();
    LDA(0, 1);         STAGE(A, brow, k1, 1, 1, 0);
    BAR(); MFMAQ(1); BAR();
    LDA(0, 2);         STAGE(Bt, bcol, ka, 0, 0, 1);
    BAR(); MFMAQ(2); BAR();
    LDA(0, 3);         STAGE(Bt, bcol, ka, 1, 0, 1);
    BAR(); MFMAQ(3);
    GATE4();
    BAR();
    LDA(1, 0); LDB(1); STAGE(A, brow, ka, 0, 0, 0);
    BAR(); MFMAQ(0); BAR();
    LDA(1, 1);         STAGE(A, brow, ka, 1, 0, 0);
    BAR(); MFMAQ(1); BAR();
    LDA(1, 2);         STAGE(Bt, bcol, kb, 0, 1, 1);
    BAR(); MFMAQ(2); BAR();
    LDA(1, 3);         STAGE(Bt, bcol, kb, 1, 1, 1);
    BAR(); MFMAQ(3);
    GATE4();
    BAR();
  }
#undef BAR
#undef GATE4

  const int batch = (int)(brow >> 9);
#pragma unroll
  for (int n = 0; n < 4; n++) {
    float t = 0.f;
#pragma unroll
    for (int m = 0; m < 8; m++)
#pragma unroll
      for (int r = 0; r < 4; r++) t += fmaxf(acc[m][n][r], 0.f);
    t += __shfl_xor(t, 16);
    t += __shfl_xor(t, 32);
    if (lane < 16)
      atomicAdd(hacc + (long)batch * F_ + bcol + wn * 64 + n * 16 + l15, t);
  }
}

// ---------------- flash attention + residual + fused column-sum (racc) + defer-max (T13).
// Writes res as fp8 (sole consumer is the fp8 FFN1); racc keeps f32 precision.
__global__ __launch_bounds__(256, 3) void attn_kernel(
    const unsigned short* __restrict__ qs, const unsigned short* __restrict__ ks,
    const unsigned short* __restrict__ vt, const unsigned short* __restrict__ q_pe,
    const int* __restrict__ qmask, const int* __restrict__ kmask,
    unsigned char* __restrict__ res8, float* __restrict__ racc) {
  __shared__ unsigned short Ks[2][64 * 64];
  __shared__ unsigned short Vs[2][64 * 64];
  __shared__ unsigned short Ps[4][32 * 64];

  const int tid = threadIdx.x, lane = tid & 63, w = tid >> 6;
  const int l15 = lane & 15, lhi = lane >> 4;
  const int h = blockIdx.x, b = blockIdx.y, q0 = blockIdx.z * 128;
  const int qlen = qmask[b], kvlen = kmask[b];

  if (q0 >= qlen) {   // whole tile query-masked: result = q_pe
    int cc = tid & 63;
    float s = 0.f;
    for (int i = 0; i < 32; i++) {
      int r = (tid >> 6) * 32 + i;
      long addr = (long)(b * T_ + q0 + r) * D_ + h * DH_ + cc;
      float v = b2f(q_pe[addr]);
      res8[addr] = f2fp8(v);
      s += v;
    }
    atomicAdd(racc + b * D_ + h * DH_ + cc, s);
    return;
  }

  bf16x8 qf[2][2];
  for (int m = 0; m < 2; m++)
    for (int k2 = 0; k2 < 2; k2++) {
      int t = q0 + w * 32 + m * 16 + l15;
      qf[m][k2] = *(const bf16x8*)(qs + (long)(b * T_ + t) * D_ + h * DH_ + k2 * 32 + lhi * 8);
    }

  f32x4 o[2][4] = {};
  float mrun[2][4], lrun[2][4];
  for (int m = 0; m < 2; m++)
    for (int r = 0; r < 4; r++) { mrun[m][r] = -3e38f; lrun[m][r] = 0.f; }

  const float SCL = 0.125f * 1.4426950408889634f;
  const float THR = 8.0f / SCL;
  const int nc = (kvlen + 63) >> 6;

  auto stage = [&](int c, int buf) {
#pragma unroll
    for (int cl = 0; cl < 2; cl++) {
      int ob = cl * 4096 + tid * 16;
      int os = ob ^ (((ob >> 7) & 7) << 4);
      int r0 = os >> 7, cb = os & 127;
      gload16(ks + (long)(b * T_ + c * 64 + r0) * D_ + h * DH_ + (cb >> 1),
              (char*)&Ks[buf][0] + ob);
      gload16(vt + ((long)(b * NH_ + h) * DH_ + r0) * T_ + c * 64 + (cb >> 1),
              (char*)&Vs[buf][0] + ob);
    }
  };

  stage(0, 0);
  int cur = 0;
  for (int c = 0; c < nc; c++) {
    const int nxt = (c + 1 < nc) ? c + 1 : c;
    stage(nxt, cur ^ 1);
    asm volatile("s_waitcnt vmcnt(4)" ::: "memory");
    __builtin_amdgcn_sched_barrier(0);
    __builtin_amdgcn_s_barrier();

    f32x4 s[2][4] = {};
    for (int k2 = 0; k2 < 2; k2++)
      for (int n = 0; n < 4; n++) {
        int key = n * 16 + l15;
        int Ab = key * 128 + (k2 * 32 + lhi * 8) * 2;
        bf16x8 kf = *(const bf16x8*)((const char*)&Ks[cur][0] + (Ab ^ ((key & 7) << 4)));
        s[0][n] = __builtin_amdgcn_mfma_f32_16x16x32_bf16(qf[0][k2], kf, s[0][n], 0, 0, 0);
        s[1][n] = __builtin_amdgcn_mfma_f32_16x16x32_bf16(qf[1][k2], kf, s[1][n], 0, 0, 0);
      }

    if (c == nc - 1) {
      for (int n = 0; n < 4; n++)
        if (c * 64 + n * 16 + l15 >= kvlen)
          for (int m = 0; m < 2; m++) s[m][n] = f32x4{-3e38f, -3e38f, -3e38f, -3e38f};
    }

    for (int m = 0; m < 2; m++) {
      float mx[4];
      for (int r = 0; r < 4; r++) {
        float v = s[m][0][r];
        for (int n = 1; n < 4; n++) v = fmaxf(v, s[m][n][r]);
        mx[r] = v;
      }
      for (int msk = 1; msk < 16; msk <<= 1)
        for (int r = 0; r < 4; r++) mx[r] = fmaxf(mx[r], __shfl_xor(mx[r], msk));
      bool grow = false;
      for (int r = 0; r < 4; r++) grow = grow || (mx[r] > mrun[m][r] + THR);
      if (__any(grow)) {
        float corr[4];
        for (int r = 0; r < 4; r++) {
          float mn = fmaxf(mrun[m][r], mx[r]);
          corr[r] = exp2f((mrun[m][r] - mn) * SCL);
          mrun[m][r] = mn;
        }
        for (int nd = 0; nd < 4; nd++)
          for (int r = 0; r < 4; r++) o[m][nd][r] *= corr[r];
        for (int r = 0; r < 4; r++) lrun[m][r] *= corr[r];
      }
      float ps[4] = {0.f, 0.f, 0.f, 0.f};
      for (int n = 0; n < 4; n++)
        for (int r = 0; r < 4; r++) {
          float pval = exp2f((s[m][n][r] - mrun[m][r]) * SCL);
          s[m][n][r] = pval;
          ps[r] += pval;
        }
      for (int msk = 1; msk < 16; msk <<= 1)
        for (int r = 0; r < 4; r++) ps[r] += __shfl_xor(ps[r], msk);
      for (int r = 0; r < 4; r++) lrun[m][r] += ps[r];
      for (int n = 0; n < 4; n++)
        for (int r = 0; r < 4; r++) {
          int row = m * 16 + lhi * 4 + r;
          int Ab = row * 128 + (n * 16 + l15) * 2;
          *(unsigned short*)((char*)&Ps[w][0] + (Ab ^ ((row & 7) << 4))) = f2bf(s[m][n][r]);
        }
    }
    asm volatile("" ::: "memory");

    for (int k4 = 0; k4 < 2; k4++) {
      bf16x8 pa[2];
      for (int m = 0; m < 2; m++) {
        int row = m * 16 + l15;
        int Ab = row * 128 + k4 * 64 + lhi * 16;
        pa[m] = *(const bf16x8*)((const char*)&Ps[w][0] + (Ab ^ ((row & 7) << 4)));
      }
      for (int nd = 0; nd < 4; nd++) {
        int dv = nd * 16 + l15;
        int Ab = dv * 128 + k4 * 64 + lhi * 16;
        bf16x8 vb = *(const bf16x8*)((const char*)&Vs[cur][0] + (Ab ^ ((dv & 7) << 4)));
        for (int m = 0; m < 2; m++)
          o[m][nd] = __builtin_amdgcn_mfma_f32_16x16x32_bf16(pa[m], vb, o[m][nd], 0, 0, 0);
      }
    }
    __builtin_amdgcn_s_barrier();
    cur ^= 1;
  }

  // epilogue: normalize, query-mask, +q_pe residual (fp8 out), fused column sums (f32)
  float cs[4] = {0.f, 0.f, 0.f, 0.f};
  for (int m = 0; m < 2; m++)
    for (int r = 0; r < 4; r++) {
      int t = q0 + w * 32 + m * 16 + lhi * 4 + r;
      float inv = 1.0f / lrun[m][r];
      bool valid = t < qlen;
      for (int nd = 0; nd < 4; nd++) {
        long addr = (long)(b * T_ + t) * D_ + h * DH_ + nd * 16 + l15;
        float v = valid ? o[m][nd][r] * inv : 0.f;
        float val = v + b2f(q_pe[addr]);
        res8[addr] = f2fp8(val);
        cs[nd] += val;
      }
    }
  for (int nd = 0; nd < 4; nd++) {
    cs[nd] += __shfl_xor(cs[nd], 16);
    cs[nd] += __shfl_xor(cs[nd], 32);
  }
  if (lane < 16)
    for (int nd = 0; nd < 4; nd++)
      atomicAdd(racc + b * D_ + h * DH_ + nd * 16 + l15, cs[nd]);
}

// out[b][n] = racc[b][n]/512 + (hacc[b][:] @ fw2[:,n]) / (512*64)
__global__ void final_kernel(const float* __restrict__ hacc, const float* __restrict__ fw2,
                             const float* __restrict__ racc, float* __restrict__ out) {
  int n = blockIdx.x * 64 + (threadIdx.x & 63);
  int bg = threadIdx.x >> 6;
  int f0 = blockIdx.y * 512;
  float acc[8] = {};
  for (int f = f0; f < f0 + 512; f++) {
    float wv = fw2[(long)f * D_ + n];
    for (int i = 0; i < 8; i++) acc[i] += hacc[(long)(bg * 8 + i) * F_ + f] * wv;
  }
  for (int i = 0; i < 8; i++) {
    float v = acc[i] * (1.0f / (512.0f * 64.0f));
    if (blockIdx.y == 0) v += racc[(long)(bg * 8 + i) * D_ + n] * (1.0f / 512.0f);
    atomicAdd(out + (bg * 8 + i) * D_ + n, v);
  }
}

// ---------------- launcher ----------------
extern "C" void kernel_launch(void* const* d_in, const int* in_sizes, int n_in,
                              void* d_out, int out_size, void* d_ws, size_t ws_size,
                              hipStream_t stream) {
  const float* queries = (const float*)d_in[0];
  const int*   qmask = (const int*)d_in[2];
  const int*   kmask = (const int*)d_in[3];
  const float* Wq  = (const float*)d_in[4];
  const float* Wk  = (const float*)d_in[5];
  const float* Wv  = (const float*)d_in[6];
  const float* fw1 = (const float*)d_in[7];
  const float* fw2 = (const float*)d_in[8];
  float* out = (float*)d_out;

  char* p = (char*)d_ws;
  auto alloc = [&](size_t bytes) -> char* {
    char* r = p; p += (bytes + 255) & ~(size_t)255; return r;
  };
  unsigned short* q_pe = (unsigned short*)alloc((size_t)BT_ * D_ * 2);
  unsigned short* k_pe = (unsigned short*)alloc((size_t)BT_ * D_ * 2);
  unsigned short* qs   = (unsigned short*)alloc((size_t)BT_ * D_ * 2);
  unsigned short* ksb  = (unsigned short*)alloc((size_t)BT_ * D_ * 2);
  unsigned short* vt   = (unsigned short*)alloc((size_t)BT_ * D_ * 2);
  unsigned char*  res8 = (unsigned char*)alloc((size_t)BT_ * D_);
  unsigned short* Wqt  = (unsigned short*)alloc((size_t)D_ * D_ * 2);
  unsigned short* Wkt  = (unsigned short*)alloc((size_t)D_ * D_ * 2);
  unsigned short* Wvt  = (unsigned short*)alloc((size_t)D_ * D_ * 2);
  unsigned short* Wkbf = (unsigned short*)alloc((size_t)D_ * D_ * 2);
  unsigned short* Wkvt = (unsigned short*)alloc((size_t)D_ * D_ * 2);
  unsigned char*  fw1t8 = (unsigned char*)alloc((size_t)D_ * F_);
  float*          racc = (float*)alloc((size_t)B_ * D_ * 4);
  float*          hacc = (float*)alloc((size_t)B_ * F_ * 4);

  hipMemsetAsync(hacc, 0, (size_t)B_ * F_ * 4, stream);
  hipMemsetAsync(racc, 0, (size_t)B_ * D_ * 4, stream);
  hipMemsetAsync(out, 0, (size_t)B_ * D_ * 4, stream);

  pack_kernel<<<BT_ * D_ / 1024, 256, 0, stream>>>(queries, q_pe, k_pe);
  prep_w<<<dim3(128, 32, 4), 256, 0, stream>>>(Wq, Wk, Wv, fw1, Wqt, Wkt, Wvt, fw1t8, Wkbf);

  // Wkvt = (Wk @ Wv)^T  (V-projection fold)
  gemm_bt<0><<<dim3(8, 8, 1), 256, 0, stream>>>(Wvt, Wkbf, Wkvt, nullptr, D_, D_, D_);

  // qs = q_pe @ Wq ; ks = k_pe @ Wk ; vt = transpose(k_pe @ (Wk@Wv))  (fused V-transpose, dead-tile skip)
  gemm8<0><<<dim3(64, 4, 3), 512, 0, stream>>>(q_pe, Wqt, qs,
                                               k_pe, Wkt, ksb,
                                               k_pe, Wkvt, vt,
                                               nullptr, D_, qmask, kmask, kmask);

  attn_kernel<<<dim3(16, 32, 4), 256, 0, stream>>>(qs, ksb, vt, q_pe, qmask, kmask, res8, racc);

  // hacc[b][f] = sum_t relu(res8 @ fw1t8^T)   (fp8, values x64)
  gemmf8<<<dim3(64, 16), 512, 0, stream>>>(res8, fw1t8, hacc);

  final_kernel<<<dim3(16, 8), 256, 0, stream>>>(hacc, fw2, racc, out);
}

// Round 12
// 379.260 us; speedup vs baseline: 1.0907x; 1.0907x over previous
//
#include <hip/hip_runtime.h>

// ---------------- problem constants ----------------
constexpr int B_  = 32;
constexpr int T_  = 512;
constexpr int D_  = 1024;
constexpr int NH_ = 16;
constexpr int DH_ = 64;
constexpr int F_  = 4096;
constexpr int BT_ = B_ * T_;   // 16384

typedef __attribute__((ext_vector_type(8))) short bf16x8;
typedef __attribute__((ext_vector_type(4))) float f32x4;
typedef __attribute__((ext_vector_type(8))) int i32x8;

#define DEVI __device__ __forceinline__

DEVI unsigned short f2bf(float f) {
  union { float f; unsigned u; } uf; uf.f = f;
  unsigned r = uf.u + 0x7fffu + ((uf.u >> 16) & 1u);   // RNE
  return (unsigned short)(r >> 16);
}
DEVI float b2f(unsigned short h) {
  union { unsigned u; float f; } uf; uf.u = ((unsigned)h) << 16;
  return uf.f;
}
DEVI unsigned char f2fp8(float f) {   // OCP e4m3, HW RNE+sat
  return (unsigned char)(__builtin_amdgcn_cvt_pk_fp8_f32(f, f, 0, false) & 0xFF);
}
// k-byte permutation within each 128B block for fp8 operands:
// position p holds logical k s.t. reading 16B at (kk*64 + lhi*16) yields k = lhi*32 + kk*16 + t
// (makes the fp8 LDS fragment reads byte-identical to the proven zero-conflict bf16 pattern).
DEVI long kperm(long c) {
  long blk = c & ~127L; int k7 = (int)(c & 127);
  return blk | (((k7 >> 4) & 1) << 6) | ((k7 >> 5) << 4) | (k7 & 15);
}
// async global->LDS, 16B per lane.
DEVI void gload16(const void* g, void* l) {
  __builtin_amdgcn_global_load_lds(
      (const __attribute__((address_space(1))) void*)(uintptr_t)g,
      (__attribute__((address_space(3))) void*)(unsigned)(uintptr_t)l, 16, 0, 0);
}
DEVI i32x8 ld32(const char* p0, const char* p1) {
  int4 lo = *(const int4*)p0, hi = *(const int4*)p1;
  i32x8 r;
  r[0] = lo.x; r[1] = lo.y; r[2] = lo.z; r[3] = lo.w;
  r[4] = hi.x; r[5] = hi.y; r[6] = hi.z; r[7] = hi.w;
  return r;
}

// ---------------- pack (PE fused): q_pe = q + pe ; k_pe = q + 2*pe   (bf16)
__global__ void pack_kernel(const float* __restrict__ q,
                            unsigned short* __restrict__ q_pe, unsigned short* __restrict__ k_pe) {
  long i = ((long)blockIdx.x * 256 + threadIdx.x) * 4;
  const float4 qv = *(const float4*)(q + i);
  int t = (int)((i >> 10) & 511);
  int j0 = (int)(i & 1023);
  float pvv[4];
#pragma unroll
  for (int u = 0; u < 4; u++) {
    int j = j0 + u;
    float inv = exp2f(-(2.0f * (float)j / 1024.0f) * 13.2877123795494f); // log2(10000)
    float ang = (float)t * inv;
    pvv[u] = ((j & 1) ? cosf(ang) : sinf(ang)) * 32.0f;
  }
  ushort4 a, b;
  a.x = f2bf(qv.x + pvv[0]); a.y = f2bf(qv.y + pvv[1]);
  a.z = f2bf(qv.z + pvv[2]); a.w = f2bf(qv.w + pvv[3]);
  b.x = f2bf(qv.x + 2.f * pvv[0]); b.y = f2bf(qv.y + 2.f * pvv[1]);
  b.z = f2bf(qv.z + 2.f * pvv[2]); b.w = f2bf(qv.w + 2.f * pvv[3]);
  *(ushort4*)(q_pe + i) = a;
  *(ushort4*)(k_pe + i) = b;
}

// merged weight prep: z in {0:Wq,1:Wk,2:Wv} -> Wt[N][K] bf16 (z==1 also emits Wkbf row-major);
// z==3: fw1 -> fw1t8[N][kperm(K)] fp8 of (fw1 * 64)  [unit-scale trick + k-permuted layout]
__global__ void prep_w(const float* __restrict__ Wq, const float* __restrict__ Wk,
                       const float* __restrict__ Wv, const float* __restrict__ fw1,
                       unsigned short* __restrict__ Wqt, unsigned short* __restrict__ Wkt,
                       unsigned short* __restrict__ Wvt, unsigned char* __restrict__ fw1t8,
                       unsigned short* __restrict__ Wkbf) {
  const int z = blockIdx.z;
  if (z < 3 && blockIdx.x >= 32) return;
  const float* W = (z == 0) ? Wq : (z == 1) ? Wk : (z == 2) ? Wv : fw1;
  unsigned short* Wt = (z == 0) ? Wqt : (z == 1) ? Wkt : Wvt;
  const int N = (z == 3) ? F_ : D_;       // cols of W
  __shared__ float tile[32][33];
  int tx = threadIdx.x & 31, ty = threadIdx.x >> 5;
  int bx = blockIdx.x, by = blockIdx.y;
  for (int i = 0; i < 4; i++) {
    int r = by * 32 + ty + i * 8;
    float v = W[(long)r * N + bx * 32 + tx];
    tile[ty + i * 8][tx] = v;
    if (z == 1) Wkbf[(long)r * D_ + bx * 32 + tx] = f2bf(v);
  }
  __syncthreads();
  for (int i = 0; i < 4; i++) {
    int r = bx * 32 + ty + i * 8;
    if (z == 3) fw1t8[(long)r * D_ + kperm(by * 32 + tx)] = f2fp8(tile[tx][ty + i * 8] * 64.0f);
    else        Wt[(long)r * D_ + by * 32 + tx] = f2bf(tile[tx][ty + i * 8]);
  }
}

// ---------------- small m97-style 128x128 GEMM (only for Wkv = Wv^T @ Wk^T fold)
template <int EPI>
__global__ __launch_bounds__(256) void gemm_bt(
    const unsigned short* __restrict__ A0, const unsigned short* __restrict__ Bt0,
    unsigned short* __restrict__ C0, float* __restrict__ hacc, int M, int N, int K) {
  __shared__ unsigned short As[128 * 32];
  __shared__ unsigned short Bs[128 * 32];
  const unsigned short* A  = A0;
  const unsigned short* Bt = Bt0;
  unsigned short* C        = C0;

  const int tid = threadIdx.x;
  const int lane = tid & 63, w = tid >> 6;
  const int wr = w >> 1, wc = w & 1;
  const int l15 = lane & 15, lhi = lane >> 4;
  const int brow = blockIdx.y * 128, bcol = blockIdx.x * 128;

  f32x4 acc[4][4] = {};
  const int o = tid * 16;
  const int srow = o >> 6;
  const int skel = (o & 63) >> 1;

  for (int kk = 0; kk < K; kk += 32) {
    gload16(A + (long)(brow + srow) * K + kk + skel,        (char*)As + o);
    gload16(A + (long)(brow + srow + 64) * K + kk + skel,   (char*)As + o + 4096);
    gload16(Bt + (long)(bcol + srow) * K + kk + skel,       (char*)Bs + o);
    gload16(Bt + (long)(bcol + srow + 64) * K + kk + skel,  (char*)Bs + o + 4096);
    __syncthreads();
    bf16x8 af[4], bfr[4];
    for (int m = 0; m < 4; m++)
      af[m] = *(const bf16x8*)((const char*)As + ((wr * 64 + m * 16 + l15) * 64 + lhi * 16));
    for (int n = 0; n < 4; n++)
      bfr[n] = *(const bf16x8*)((const char*)Bs + ((wc * 64 + n * 16 + l15) * 64 + lhi * 16));
    for (int m = 0; m < 4; m++)
      for (int n = 0; n < 4; n++)
        acc[m][n] = __builtin_amdgcn_mfma_f32_16x16x32_bf16(af[m], bfr[n], acc[m][n], 0, 0, 0);
    __syncthreads();
  }

  for (int m = 0; m < 4; m++)
    for (int n = 0; n < 4; n++) {
      int row = brow + wr * 64 + m * 16 + lhi * 4;
      int col = bcol + wc * 64 + n * 16 + l15;
      for (int r = 0; r < 4; r++)
        C[(long)(row + r) * N + col] = f2bf(acc[m][n][r]);
    }
}

// ---------------- 256x256 8-phase GEMM bf16 (R5 schedule) — QKV projections.
// EPI==0: z<2 store bf16 C; z==2 store V transposed into vt[(b*16+h)*64+j][t] (coalesced via LDS).
// L (optional): per-batch live-row count; row-tile 1 of batch b is dead if L[b] <= 256.
template <int EPI>
__global__ __launch_bounds__(512, 2) void gemm8(
    const unsigned short* __restrict__ A0, const unsigned short* __restrict__ Bt0, unsigned short* __restrict__ C0,
    const unsigned short* __restrict__ A1, const unsigned short* __restrict__ Bt1, unsigned short* __restrict__ C1,
    const unsigned short* __restrict__ A2, const unsigned short* __restrict__ Bt2, unsigned short* __restrict__ C2,
    float* __restrict__ hacc, int N,
    const int* __restrict__ L0, const int* __restrict__ L1, const int* __restrict__ L2) {
  constexpr int K = 1024, NK = 16, NI = 8;
  __shared__ char lds[2][2][32768];

  const int z = blockIdx.z;
  const unsigned short* A  = (z == 0) ? A0  : (z == 1 ? A1  : A2);
  const unsigned short* Bt = (z == 0) ? Bt0 : (z == 1 ? Bt1 : Bt2);
  unsigned short* C        = (z == 0) ? C0  : (z == 1 ? C1  : C2);
  const int* L             = (z == 0) ? L0  : (z == 1 ? L1  : L2);

  const long brow = (long)blockIdx.x * 256, bcol = (long)blockIdx.y * 256;
  if (L && (brow & 256) && L[brow >> 9] <= 256) return;   // dead row-tile

  const int tid = threadIdx.x;
  const int lane = tid & 63, w = tid >> 6;
  const int wm = w >> 2, wn = w & 3;
  const int l15 = lane & 15, lhi = lane >> 4;

  const int drow = (tid * 16) >> 7;
  const int dcol = ((tid * 16) & 127) ^ ((drow & 7) << 4);
  const int sw   = (l15 & 7) << 4;

  f32x4 acc[8][4] = {};
  bf16x8 bfr[4][2], af[2][2];

  auto STAGE = [&](const unsigned short* __restrict__ P, long tb, int kt, int h, int buf, int op) {
    const unsigned short* g = P + (tb + h * 128 + drow) * (long)K + kt * 64 + (dcol >> 1);
    char* l = &lds[buf][op][h * 16384 + tid * 16];
    gload16(g, l);
    gload16(g + 64L * K, l + 8192);
  };
  auto LDA = [&](int buf, int q) {
#pragma unroll
    for (int mi = 0; mi < 2; mi++) {
      int row = wm * 128 + (q * 2 + mi) * 16 + l15;
#pragma unroll
      for (int kk = 0; kk < 2; kk++)
        af[mi][kk] = *(const bf16x8*)(&lds[buf][0][0] + (row << 7) + ((kk * 64 + lhi * 16) ^ sw));
    }
  };
  auto LDB = [&](int buf) {
#pragma unroll
    for (int n = 0; n < 4; n++) {
      int row = wn * 64 + n * 16 + l15;
#pragma unroll
      for (int kk = 0; kk < 2; kk++)
        bfr[n][kk] = *(const bf16x8*)(&lds[buf][1][0] + (row << 7) + ((kk * 64 + lhi * 16) ^ sw));
    }
  };
  auto MFMAQ = [&](int q) {
    __builtin_amdgcn_s_setprio(1);
#pragma unroll
    for (int mi = 0; mi < 2; mi++)
#pragma unroll
      for (int n = 0; n < 4; n++)
#pragma unroll
        for (int kk = 0; kk < 2; kk++)
          acc[q * 2 + mi][n] =
              __builtin_amdgcn_mfma_f32_16x16x32_bf16(af[mi][kk], bfr[n][kk], acc[q * 2 + mi][n], 0, 0, 0);
    __builtin_amdgcn_s_setprio(0);
  };
#define BAR() __builtin_amdgcn_s_barrier()
#define GATE4() asm volatile("s_waitcnt vmcnt(4)" ::: "memory")

  STAGE(A, brow, 0, 0, 0, 0);  STAGE(A, brow, 0, 1, 0, 0);
  STAGE(Bt, bcol, 0, 0, 0, 1); STAGE(Bt, bcol, 0, 1, 0, 1);
  STAGE(Bt, bcol, 1, 0, 1, 1); STAGE(Bt, bcol, 1, 1, 1, 1);
  GATE4();
  BAR();

  for (int i = 0; i < NI; ++i) {
    const int k1 = 2 * i + 1;
    const int ka = (2 * i + 2) & (NK - 1);
    const int kb = (2 * i + 3) & (NK - 1);
    LDA(0, 0); LDB(0); STAGE(A, brow, k1, 0, 1, 0);
    BAR(); MFMAQ(0); BAR();
    LDA(0, 1);         STAGE(A, brow, k1, 1, 1, 0);
    BAR(); MFMAQ(1); BAR();
    LDA(0, 2);         STAGE(Bt, bcol, ka, 0, 0, 1);
    BAR(); MFMAQ(2); BAR();
    LDA(0, 3);         STAGE(Bt, bcol, ka, 1, 0, 1);
    BAR(); MFMAQ(3);
    GATE4();
    BAR();
    LDA(1, 0); LDB(1); STAGE(A, brow, ka, 0, 0, 0);
    BAR(); MFMAQ(0); BAR();
    LDA(1, 1);         STAGE(A, brow, ka, 1, 0, 0);
    BAR(); MFMAQ(1); BAR();
    LDA(1, 2);         STAGE(Bt, bcol, kb, 0, 1, 1);
    BAR(); MFMAQ(2); BAR();
    LDA(1, 3);         STAGE(Bt, bcol, kb, 1, 1, 1);
    BAR(); MFMAQ(3);
    GATE4();
    BAR();
  }
#undef BAR
#undef GATE4

  if (EPI == 0) {
    if (z == 2) {
      asm volatile("s_waitcnt vmcnt(0)" ::: "memory");
      __builtin_amdgcn_s_barrier();
      char* tl = &lds[0][0][0] + (w << 14);
#pragma unroll
      for (int m = 0; m < 8; m++)
#pragma unroll
        for (int n = 0; n < 4; n++) {
          int cl = n * 16 + l15;
#pragma unroll
          for (int r = 0; r < 4; r++) {
            int tofs = m * 16 + lhi * 4 + r;
            *(unsigned short*)(tl + cl * 256 + ((tofs * 2) ^ ((cl & 7) << 4))) = f2bf(acc[m][n][r]);
          }
        }
      asm volatile("" ::: "memory");
      const int bb = (int)(brow >> 9), t0 = (int)(brow & 511);
#pragma unroll
      for (int rr = 0; rr < 16; rr++) {
        int row = rr * 4 + lhi;
        bf16x8 v = *(const bf16x8*)(tl + row * 256 + ((l15 * 16) ^ ((row & 7) << 4)));
        int gcol = (int)bcol + wn * 64 + row;
        long vtrow = ((long)(bb * NH_ + (gcol >> 6))) * DH_ + (gcol & 63);
        *(bf16x8*)(C + vtrow * T_ + t0 + wm * 128 + l15 * 8) = v;
      }
    } else {
#pragma unroll
      for (int m = 0; m < 8; m++)
#pragma unroll
        for (int n = 0; n < 4; n++) {
          long row = brow + wm * 128 + m * 16 + lhi * 4;
          long col = bcol + wn * 64 + n * 16 + l15;
#pragma unroll
          for (int r = 0; r < 4; r++)
            C[(row + r) * (long)N + col] = f2bf(acc[m][n][r]);
        }
    }
  } else {
    const int batch = (int)(brow >> 9);
#pragma unroll
    for (int n = 0; n < 4; n++) {
      float t = 0.f;
#pragma unroll
      for (int m = 0; m < 8; m++)
#pragma unroll
        for (int r = 0; r < 4; r++) t += fmaxf(acc[m][n][r], 0.f);
      t += __shfl_xor(t, 16);
      t += __shfl_xor(t, 32);
      if (lane < 16)
        atomicAdd(hacc + (long)batch * F_ + bcol + wn * 64 + n * 16 + l15, t);
    }
  }
}

// ---------------- FFN1 in fp8: hacc[b][f] = sum_t relu(res8 @ fw1t8^T)  (values carry x64 from fw1)
// Operands stored k-permuted (kperm) so LDS fragment reads use the proven bf16 zero-conflict pattern.
__global__ __launch_bounds__(512, 2) void gemmf8(
    const unsigned char* __restrict__ A, const unsigned char* __restrict__ Bt,
    float* __restrict__ hacc) {
  constexpr int K = 1024, NKT = 8, NI = 4;
  __shared__ char lds[2][2][32768];
  const long brow = (long)blockIdx.x * 256, bcol = (long)blockIdx.y * 256;
  const int tid = threadIdx.x;
  const int lane = tid & 63, w = tid >> 6;
  const int wm = w >> 2, wn = w & 3;
  const int l15 = lane & 15, lhi = lane >> 4;

  const int drow = (tid * 16) >> 7;
  const int dcol = ((tid * 16) & 127) ^ ((drow & 7) << 4);
  const int sw   = (l15 & 7) << 4;

  f32x4 acc[8][4] = {};
  i32x8 af[2], bfr[4];

  auto STAGE = [&](const unsigned char* __restrict__ P, long tb, int kt, int h, int buf, int op) {
    const unsigned char* g = P + (tb + h * 128 + drow) * (long)K + kt * 128 + dcol;
    char* l = &lds[buf][op][h * 16384 + tid * 16];
    gload16(g, l);
    gload16(g + 64L * K, l + 8192);
  };
  // fragment reads: two 16B at (kk*64 + lhi*16)^sw — byte-identical to the bf16 pattern;
  // k-permuted storage makes the concatenation equal logical k = lhi*32 .. lhi*32+31.
  auto LDA = [&](int buf, int q) {
#pragma unroll
    for (int mi = 0; mi < 2; mi++) {
      int row = wm * 128 + (q * 2 + mi) * 16 + l15;
      const char* base = &lds[buf][0][0] + (row << 7);
      af[mi] = ld32(base + ((lhi * 16) ^ sw), base + ((64 + lhi * 16) ^ sw));
    }
  };
  auto LDB = [&](int buf) {
#pragma unroll
    for (int n = 0; n < 4; n++) {
      int row = wn * 64 + n * 16 + l15;
      const char* base = &lds[buf][1][0] + (row << 7);
      bfr[n] = ld32(base + ((lhi * 16) ^ sw), base + ((64 + lhi * 16) ^ sw));
    }
  };
  auto MFMAQ = [&](int q) {
    __builtin_amdgcn_s_setprio(1);
#pragma unroll
    for (int mi = 0; mi < 2; mi++)
#pragma unroll
      for (int n = 0; n < 4; n++)
        acc[q * 2 + mi][n] = __builtin_amdgcn_mfma_scale_f32_16x16x128_f8f6f4(
            af[mi], bfr[n], acc[q * 2 + mi][n], 0, 0,
            0, 0x7F7F7F7F, 0, 0x7F7F7F7F);   // fp8 x fp8, unit e8m0 scales
    __builtin_amdgcn_s_setprio(0);
  };
#define BAR() __builtin_amdgcn_s_barrier()
#define GATE4() asm volatile("s_waitcnt vmcnt(4)" ::: "memory")

  STAGE(A, brow, 0, 0, 0, 0);  STAGE(A, brow, 0, 1, 0, 0);
  STAGE(Bt, bcol, 0, 0, 0, 1); STAGE(Bt, bcol, 0, 1, 0, 1);
  STAGE(Bt, bcol, 1, 0, 1, 1); STAGE(Bt, bcol, 1, 1, 1, 1);
  GATE4();
  BAR();

  for (int i = 0; i < NI; ++i) {
    const int k1 = 2 * i + 1;
    const int ka = (2 * i + 2) & (NKT - 1);
    const int kb = (2 * i + 3) & (NKT - 1);
    LDA(0, 0); LDB(0); STAGE(A, brow, k1, 0, 1, 0);
    BAR(); MFMAQ(0); BAR();
    LDA(0, 1);         STAGE(A, brow, k1, 1, 1, 0);
    BAR(); MFMAQ(1); BAR();
    LDA(0, 2);         STAGE(Bt, bcol, ka, 0, 0, 1);
    BAR(); MFMAQ(2); BAR();
    LDA(0, 3);         STAGE(Bt, bcol, ka, 1, 0, 1);
    BAR(); MFMAQ(3);
    GATE4();
    BAR();
    LDA(1, 0); LDB(1); STAGE(A, brow, ka, 0, 0, 0);
    BAR(); MFMAQ(0); BAR();
    LDA(1, 1);         STAGE(A, brow, ka, 1, 0, 0);
    BAR(); MFMAQ(1); BAR();
    LDA(1, 2);         STAGE(Bt, bcol, kb, 0, 1, 1);
    BAR(); MFMAQ(2); BAR();
    LDA(1, 3);         STAGE(Bt, bcol, kb, 1, 1, 1);
    BAR(); MFMAQ(3);
    GATE4();
    BAR();
  }
#undef BAR
#undef GATE4

  const int batch = (int)(brow >> 9);
#pragma unroll
  for (int n = 0; n < 4; n++) {
    float t = 0.f;
#pragma unroll
    for (int m = 0; m < 8; m++)
#pragma unroll
      for (int r = 0; r < 4; r++) t += fmaxf(acc[m][n][r], 0.f);
    t += __shfl_xor(t, 16);
    t += __shfl_xor(t, 32);
    if (lane < 16)
      atomicAdd(hacc + (long)batch * F_ + bcol + wn * 64 + n * 16 + l15, t);
  }
}

// ---------------- flash attention + residual + fused column-sum (racc) + defer-max (T13).
// Writes res as fp8 in the k-permuted layout (sole consumer is the fp8 FFN1).
__global__ __launch_bounds__(256, 3) void attn_kernel(
    const unsigned short* __restrict__ qs, const unsigned short* __restrict__ ks,
    const unsigned short* __restrict__ vt, const unsigned short* __restrict__ q_pe,
    const int* __restrict__ qmask, const int* __restrict__ kmask,
    unsigned char* __restrict__ res8, float* __restrict__ racc) {
  __shared__ unsigned short Ks[2][64 * 64];
  __shared__ unsigned short Vs[2][64 * 64];
  __shared__ unsigned short Ps[4][32 * 64];

  const int tid = threadIdx.x, lane = tid & 63, w = tid >> 6;
  const int l15 = lane & 15, lhi = lane >> 4;
  const int h = blockIdx.x, b = blockIdx.y, q0 = blockIdx.z * 128;
  const int qlen = qmask[b], kvlen = kmask[b];

  if (q0 >= qlen) {   // whole tile query-masked: result = q_pe
    int cc = tid & 63;
    float s = 0.f;
    for (int i = 0; i < 32; i++) {
      int r = (tid >> 6) * 32 + i;
      long rb = (long)(b * T_ + q0 + r) * D_;
      long col = h * DH_ + cc;
      float v = b2f(q_pe[rb + col]);
      res8[rb + kperm(col)] = f2fp8(v);
      s += v;
    }
    atomicAdd(racc + b * D_ + h * DH_ + cc, s);
    return;
  }

  bf16x8 qf[2][2];
  for (int m = 0; m < 2; m++)
    for (int k2 = 0; k2 < 2; k2++) {
      int t = q0 + w * 32 + m * 16 + l15;
      qf[m][k2] = *(const bf16x8*)(qs + (long)(b * T_ + t) * D_ + h * DH_ + k2 * 32 + lhi * 8);
    }

  f32x4 o[2][4] = {};
  float mrun[2][4], lrun[2][4];
  for (int m = 0; m < 2; m++)
    for (int r = 0; r < 4; r++) { mrun[m][r] = -3e38f; lrun[m][r] = 0.f; }

  const float SCL = 0.125f * 1.4426950408889634f;
  const float THR = 8.0f / SCL;
  const int nc = (kvlen + 63) >> 6;

  auto stage = [&](int c, int buf) {
#pragma unroll
    for (int cl = 0; cl < 2; cl++) {
      int ob = cl * 4096 + tid * 16;
      int os = ob ^ (((ob >> 7) & 7) << 4);
      int r0 = os >> 7, cb = os & 127;
      gload16(ks + (long)(b * T_ + c * 64 + r0) * D_ + h * DH_ + (cb >> 1),
              (char*)&Ks[buf][0] + ob);
      gload16(vt + ((long)(b * NH_ + h) * DH_ + r0) * T_ + c * 64 + (cb >> 1),
              (char*)&Vs[buf][0] + ob);
    }
  };

  stage(0, 0);
  int cur = 0;
  for (int c = 0; c < nc; c++) {
    const int nxt = (c + 1 < nc) ? c + 1 : c;
    stage(nxt, cur ^ 1);
    asm volatile("s_waitcnt vmcnt(4)" ::: "memory");
    __builtin_amdgcn_sched_barrier(0);
    __builtin_amdgcn_s_barrier();

    f32x4 s[2][4] = {};
    for (int k2 = 0; k2 < 2; k2++)
      for (int n = 0; n < 4; n++) {
        int key = n * 16 + l15;
        int Ab = key * 128 + (k2 * 32 + lhi * 8) * 2;
        bf16x8 kf = *(const bf16x8*)((const char*)&Ks[cur][0] + (Ab ^ ((key & 7) << 4)));
        s[0][n] = __builtin_amdgcn_mfma_f32_16x16x32_bf16(qf[0][k2], kf, s[0][n], 0, 0, 0);
        s[1][n] = __builtin_amdgcn_mfma_f32_16x16x32_bf16(qf[1][k2], kf, s[1][n], 0, 0, 0);
      }

    if (c == nc - 1) {
      for (int n = 0; n < 4; n++)
        if (c * 64 + n * 16 + l15 >= kvlen)
          for (int m = 0; m < 2; m++) s[m][n] = f32x4{-3e38f, -3e38f, -3e38f, -3e38f};
    }

    for (int m = 0; m < 2; m++) {
      float mx[4];
      for (int r = 0; r < 4; r++) {
        float v = s[m][0][r];
        for (int n = 1; n < 4; n++) v = fmaxf(v, s[m][n][r]);
        mx[r] = v;
      }
      for (int msk = 1; msk < 16; msk <<= 1)
        for (int r = 0; r < 4; r++) mx[r] = fmaxf(mx[r], __shfl_xor(mx[r], msk));
      bool grow = false;
      for (int r = 0; r < 4; r++) grow = grow || (mx[r] > mrun[m][r] + THR);
      if (__any(grow)) {
        float corr[4];
        for (int r = 0; r < 4; r++) {
          float mn = fmaxf(mrun[m][r], mx[r]);
          corr[r] = exp2f((mrun[m][r] - mn) * SCL);
          mrun[m][r] = mn;
        }
        for (int nd = 0; nd < 4; nd++)
          for (int r = 0; r < 4; r++) o[m][nd][r] *= corr[r];
        for (int r = 0; r < 4; r++) lrun[m][r] *= corr[r];
      }
      float ps[4] = {0.f, 0.f, 0.f, 0.f};
      for (int n = 0; n < 4; n++)
        for (int r = 0; r < 4; r++) {
          float pval = exp2f((s[m][n][r] - mrun[m][r]) * SCL);
          s[m][n][r] = pval;
          ps[r] += pval;
        }
      for (int msk = 1; msk < 16; msk <<= 1)
        for (int r = 0; r < 4; r++) ps[r] += __shfl_xor(ps[r], msk);
      for (int r = 0; r < 4; r++) lrun[m][r] += ps[r];
      for (int n = 0; n < 4; n++)
        for (int r = 0; r < 4; r++) {
          int row = m * 16 + lhi * 4 + r;
          int Ab = row * 128 + (n * 16 + l15) * 2;
          *(unsigned short*)((char*)&Ps[w][0] + (Ab ^ ((row & 7) << 4))) = f2bf(s[m][n][r]);
        }
    }
    asm volatile("" ::: "memory");

    for (int k4 = 0; k4 < 2; k4++) {
      bf16x8 pa[2];
      for (int m = 0; m < 2; m++) {
        int row = m * 16 + l15;
        int Ab = row * 128 + k4 * 64 + lhi * 16;
        pa[m] = *(const bf16x8*)((const char*)&Ps[w][0] + (Ab ^ ((row & 7) << 4)));
      }
      for (int nd = 0; nd < 4; nd++) {
        int dv = nd * 16 + l15;
        int Ab = dv * 128 + k4 * 64 + lhi * 16;
        bf16x8 vb = *(const bf16x8*)((const char*)&Vs[cur][0] + (Ab ^ ((dv & 7) << 4)));
        for (int m = 0; m < 2; m++)
          o[m][nd] = __builtin_amdgcn_mfma_f32_16x16x32_bf16(pa[m], vb, o[m][nd], 0, 0, 0);
      }
    }
    __builtin_amdgcn_s_barrier();
    cur ^= 1;
  }

  // epilogue: normalize, query-mask, +q_pe residual (fp8 out, k-permuted), fused column sums (f32)
  float cs[4] = {0.f, 0.f, 0.f, 0.f};
  for (int m = 0; m < 2; m++)
    for (int r = 0; r < 4; r++) {
      int t = q0 + w * 32 + m * 16 + lhi * 4 + r;
      float inv = 1.0f / lrun[m][r];
      bool valid = t < qlen;
      long rb = (long)(b * T_ + t) * D_;
      for (int nd = 0; nd < 4; nd++) {
        long col = h * DH_ + nd * 16 + l15;
        float v = valid ? o[m][nd][r] * inv : 0.f;
        float val = v + b2f(q_pe[rb + col]);
        res8[rb + kperm(col)] = f2fp8(val);
        cs[nd] += val;
      }
    }
  for (int nd = 0; nd < 4; nd++) {
    cs[nd] += __shfl_xor(cs[nd], 16);
    cs[nd] += __shfl_xor(cs[nd], 32);
  }
  if (lane < 16)
    for (int nd = 0; nd < 4; nd++)
      atomicAdd(racc + b * D_ + h * DH_ + nd * 16 + l15, cs[nd]);
}

// out[b][n] = racc[b][n]/512 + (hacc[b][:] @ fw2[:,n]) / (512*64)
__global__ void final_kernel(const float* __restrict__ hacc, const float* __restrict__ fw2,
                             const float* __restrict__ racc, float* __restrict__ out) {
  int n = blockIdx.x * 64 + (threadIdx.x & 63);
  int bg = threadIdx.x >> 6;
  int f0 = blockIdx.y * 512;
  float acc[8] = {};
  for (int f = f0; f < f0 + 512; f++) {
    float wv = fw2[(long)f * D_ + n];
    for (int i = 0; i < 8; i++) acc[i] += hacc[(long)(bg * 8 + i) * F_ + f] * wv;
  }
  for (int i = 0; i < 8; i++) {
    float v = acc[i] * (1.0f / (512.0f * 64.0f));
    if (blockIdx.y == 0) v += racc[(long)(bg * 8 + i) * D_ + n] * (1.0f / 512.0f);
    atomicAdd(out + (bg * 8 + i) * D_ + n, v);
  }
}

// ---------------- launcher ----------------
extern "C" void kernel_launch(void* const* d_in, const int* in_sizes, int n_in,
                              void* d_out, int out_size, void* d_ws, size_t ws_size,
                              hipStream_t stream) {
  const float* queries = (const float*)d_in[0];
  const int*   qmask = (const int*)d_in[2];
  const int*   kmask = (const int*)d_in[3];
  const float* Wq  = (const float*)d_in[4];
  const float* Wk  = (const float*)d_in[5];
  const float* Wv  = (const float*)d_in[6];
  const float* fw1 = (const float*)d_in[7];
  const float* fw2 = (const float*)d_in[8];
  float* out = (float*)d_out;

  char* p = (char*)d_ws;
  auto alloc = [&](size_t bytes) -> char* {
    char* r = p; p += (bytes + 255) & ~(size_t)255; return r;
  };
  unsigned short* q_pe = (unsigned short*)alloc((size_t)BT_ * D_ * 2);
  unsigned short* k_pe = (unsigned short*)alloc((size_t)BT_ * D_ * 2);
  unsigned short* qs   = (unsigned short*)alloc((size_t)BT_ * D_ * 2);
  unsigned short* ksb  = (unsigned short*)alloc((size_t)BT_ * D_ * 2);
  unsigned short* vt   = (unsigned short*)alloc((size_t)BT_ * D_ * 2);
  unsigned char*  res8 = (unsigned char*)alloc((size_t)BT_ * D_);
  unsigned short* Wqt  = (unsigned short*)alloc((size_t)D_ * D_ * 2);
  unsigned short* Wkt  = (unsigned short*)alloc((size_t)D_ * D_ * 2);
  unsigned short* Wvt  = (unsigned short*)alloc((size_t)D_ * D_ * 2);
  unsigned short* Wkbf = (unsigned short*)alloc((size_t)D_ * D_ * 2);
  unsigned short* Wkvt = (unsigned short*)alloc((size_t)D_ * D_ * 2);
  unsigned char*  fw1t8 = (unsigned char*)alloc((size_t)D_ * F_);
  float*          racc = (float*)alloc((size_t)B_ * D_ * 4);
  float*          hacc = (float*)alloc((size_t)B_ * F_ * 4);

  hipMemsetAsync(hacc, 0, (size_t)B_ * F_ * 4, stream);
  hipMemsetAsync(racc, 0, (size_t)B_ * D_ * 4, stream);
  hipMemsetAsync(out, 0, (size_t)B_ * D_ * 4, stream);

  pack_kernel<<<BT_ * D_ / 1024, 256, 0, stream>>>(queries, q_pe, k_pe);
  prep_w<<<dim3(128, 32, 4), 256, 0, stream>>>(Wq, Wk, Wv, fw1, Wqt, Wkt, Wvt, fw1t8, Wkbf);

  // Wkvt = (Wk @ Wv)^T  (V-projection fold)
  gemm_bt<0><<<dim3(8, 8, 1), 256, 0, stream>>>(Wvt, Wkbf, Wkvt, nullptr, D_, D_, D_);

  // qs = q_pe @ Wq ; ks = k_pe @ Wk ; vt = transpose(k_pe @ (Wk@Wv))  (fused V-transpose, dead-tile skip)
  gemm8<0><<<dim3(64, 4, 3), 512, 0, stream>>>(q_pe, Wqt, qs,
                                               k_pe, Wkt, ksb,
                                               k_pe, Wkvt, vt,
                                               nullptr, D_, qmask, kmask, kmask);

  attn_kernel<<<dim3(16, 32, 4), 256, 0, stream>>>(qs, ksb, vt, q_pe, qmask, kmask, res8, racc);

  // hacc[b][f] = sum_t relu(res8 @ fw1t8^T)   (fp8, values x64, k-permuted operands)
  gemmf8<<<dim3(64, 16), 512, 0, stream>>>(res8, fw1t8, hacc);

  final_kernel<<<dim3(16, 8), 256, 0, stream>>>(hacc, fw2, racc, out);
}